// Round 9
// baseline (64.019 us; speedup 1.0000x reference)
//
#include <hip/hip_runtime.h>

#define T_SEQ 2048
#define DIMM 512
#define NH 8
#define HD 64
#define BB 2
#define CHUNK 64
#define NCHUNK 32
#define EPSV 1e-6f
#define LDST 72    // bf16 LDS row stride (shorts) for the small kernels
#define CST 66     // proj epilogue bounce-tile row stride (shorts)

typedef __attribute__((ext_vector_type(8))) short bf16x8;
typedef __attribute__((ext_vector_type(4))) short s16x4;
typedef __attribute__((ext_vector_type(4))) float f32x4;

static __device__ inline short f2bf(float f) {
    union { float f; unsigned u; } v; v.f = f;
    unsigned r = v.u + 0x7FFFu + ((v.u >> 16) & 1u);
    return (short)(r >> 16);
}
static __device__ inline float bf2f(short s) {
    union { unsigned u; float f; } v; v.u = ((unsigned)(unsigned short)s) << 16;
    return v.f;
}
static __device__ __forceinline__ void gload_lds16(const void* g, void* l) {
    __builtin_amdgcn_global_load_lds(
        (__attribute__((address_space(1))) void*)g,
        (__attribute__((address_space(3))) void*)l, 16, 0, 0);
}

// ---------------------------------------------------------------------------
// Kernel 0: fp32 -> bf16. x -> xb; {Wq,Wk,Wv} -> Wcat[1536][512]; Wo -> Wob.
// grid 1536, block 256
// ---------------------------------------------------------------------------
__global__ __launch_bounds__(256) void convert_kernel(
    const float* __restrict__ x, const float* __restrict__ Wq,
    const float* __restrict__ Wk, const float* __restrict__ Wv,
    const float* __restrict__ Wo,
    short* __restrict__ xb, short* __restrict__ Wcat, short* __restrict__ Wob)
{
    const int u = blockIdx.x * 256 + threadIdx.x;   // 8-float unit id
    const float* src; short* dst;
    if (u < 262144) {
        src = x + (size_t)u * 8; dst = xb + (size_t)u * 8;
    } else {
        const int v = u - 262144;
        const int o = (v & 32767) * 8;
        if (v < 32768)       { src = Wq + o; dst = Wcat + o; }
        else if (v < 65536)  { src = Wk + o; dst = Wcat + 262144 + o; }
        else if (v < 98304)  { src = Wv + o; dst = Wcat + 524288 + o; }
        else                 { src = Wo + o; dst = Wob + o; }
    }
    const float4 a = *(const float4*)src;
    const float4 b = *(const float4*)(src + 4);
    *(bf16x8*)dst = (bf16x8){f2bf(a.x), f2bf(a.y), f2bf(a.z), f2bf(a.w),
                             f2bf(b.x), f2bf(b.y), f2bf(b.z), f2bf(b.w)};
}

// ---------------------------------------------------------------------------
// Kernel 1: fused QKV projection GEMM, 64x64 tiles (outproj-proven shape).
// C[4096][1536] = xb @ Wcat^T; each block owns one (m-tile, head-column):
//   nblk 0-7   (Q): serial-row softmax -> Qs [b,h,t,d]
//   nblk 8-15  (K): elu+1 -> Kbf [b,h,t,d] and Ktb [b,h,d,t]
//   nblk 16-23 (V): -> Vt [b,h,e,t]
// grid (24, 64), block 256 (4 waves, each 16x64 output); 16 KB LDS
// ---------------------------------------------------------------------------
__global__ __launch_bounds__(256) void proj_mfma_kernel(
    const short* __restrict__ xb, const short* __restrict__ Wcat,
    short* __restrict__ Qs, short* __restrict__ Kbf,
    short* __restrict__ Ktb, short* __restrict__ Vt)
{
    __shared__ short S[8192];   // 16 KB: As[64][64] | Bs[64][64]; Cs aliases
    short* As = S;
    short* Bs = S + 4096;
    short* Cs = S;              // [64][CST] = 4224 shorts
    const int nblk = blockIdx.x;          // 0..23
    const int m0 = blockIdx.y * 64;
    const int n0 = nblk * 64;             // row into stacked Wcat[1536]
    const int which = nblk >> 3;
    const int head = nblk & 7;
    const int tid = threadIdx.x;
    const int lane = tid & 63, w = tid >> 6;
    const int fr = lane & 15, fg = lane >> 4;
    const int lr = lane >> 3, lc = (lane & 7) * 8;
    f32x4 acc[4] = {};
    for (int k0 = 0; k0 < DIMM; k0 += 64) {
        #pragma unroll
        for (int it = 0; it < 2; it++) {
            const int r0 = w * 16 + it * 8;
            gload_lds16(xb + (size_t)(m0 + r0 + lr) * DIMM + k0 + lc, &As[r0 * 64]);
            gload_lds16(Wcat + (size_t)(n0 + r0 + lr) * DIMM + k0 + lc, &Bs[r0 * 64]);
        }
        __syncthreads();
        #pragma unroll
        for (int ks = 0; ks < 2; ks++) {
            const bf16x8 af = *(const bf16x8*)&As[(w * 16 + fr) * 64 + ks * 32 + fg * 8];
            #pragma unroll
            for (int j = 0; j < 4; j++) {
                const bf16x8 bfr = *(const bf16x8*)&Bs[(j * 16 + fr) * 64 + ks * 32 + fg * 8];
                acc[j] = __builtin_amdgcn_mfma_f32_16x16x32_bf16(af, bfr, acc[j], 0, 0, 0);
            }
        }
        __syncthreads();
    }
    // bounce acc -> Cs[64][66] (elu+1 fused for K); stride 66: row-reads 2-way,
    // col-reads conflict-free, stores conflict-free
    #pragma unroll
    for (int j = 0; j < 4; j++)
        #pragma unroll
        for (int reg = 0; reg < 4; reg++) {
            float val = acc[j][reg];
            if (which == 1) val = (val > 0.f) ? (val + 1.f) : __expf(val);
            Cs[(w * 16 + fg * 4 + reg) * CST + j * 16 + fr] = f2bf(val);
        }
    __syncthreads();

    const int b = m0 >> 11, t0 = m0 & (T_SEQ - 1);
    if (which == 0) {
        if (tid < 64) {
            const unsigned* cr = (const unsigned*)&Cs[tid * CST];   // 32 u32, 4B-aligned
            unsigned u[32];
            #pragma unroll
            for (int s = 0; s < 32; s++) u[s] = cr[s];
            float mx = -1e30f;
            #pragma unroll
            for (int s = 0; s < 32; s++) {
                mx = fmaxf(mx, bf2f((short)(u[s] & 0xffff)));
                mx = fmaxf(mx, bf2f((short)(u[s] >> 16)));
            }
            float sum = 0.f;
            #pragma unroll
            for (int s = 0; s < 32; s++) {
                sum += __expf(bf2f((short)(u[s] & 0xffff)) - mx);
                sum += __expf(bf2f((short)(u[s] >> 16)) - mx);
            }
            const float inv = 1.f / sum;
            short* qp = Qs + (((size_t)(b * NH + head)) * T_SEQ + t0 + tid) * HD;
            #pragma unroll
            for (int g = 0; g < 8; g++) {
                bf16x8 o;
                #pragma unroll
                for (int k = 0; k < 4; k++) {
                    const unsigned uv = u[g * 4 + k];
                    o[2 * k]     = f2bf(__expf(bf2f((short)(uv & 0xffff)) - mx) * inv);
                    o[2 * k + 1] = f2bf(__expf(bf2f((short)(uv >> 16)) - mx) * inv);
                }
                *(bf16x8*)(qp + g * 8) = o;
            }
        }
    } else if (which == 1) {
        // Kbf row copy (already elu'd in Cs)
        if (tid < 64) {
            const unsigned* cr = (const unsigned*)&Cs[tid * CST];
            short* kp = Kbf + (((size_t)(b * NH + head)) * T_SEQ + t0 + tid) * HD;
            #pragma unroll
            for (int g = 0; g < 8; g++) {
                bf16x8 o;
                #pragma unroll
                for (int k = 0; k < 4; k++) {
                    const unsigned uv = cr[g * 4 + k];
                    o[2 * k]     = (short)(uv & 0xffff);
                    o[2 * k + 1] = (short)(uv >> 16);
                }
                *(bf16x8*)(kp + g * 8) = o;
            }
        }
        // Ktb transpose: thread (c, q) -> rows q*16..q*16+15 of column c
        {
            const int c = tid & 63, q = tid >> 6;
            short* ktp = Ktb + (((size_t)(b * NH + head)) * HD + c) * T_SEQ + t0 + q * 16;
            #pragma unroll
            for (int s = 0; s < 2; s++) {
                bf16x8 o;
                #pragma unroll
                for (int k = 0; k < 8; k++) o[k] = Cs[(q * 16 + s * 8 + k) * CST + c];
                *(bf16x8*)(ktp + s * 8) = o;
            }
        }
    } else {
        // Vt transpose
        const int c = tid & 63, q = tid >> 6;
        short* vtp = Vt + (((size_t)(b * NH + head)) * HD + c) * T_SEQ + t0 + q * 16;
        #pragma unroll
        for (int s = 0; s < 2; s++) {
            bf16x8 o;
            #pragma unroll
            for (int k = 0; k < 8; k++) o[k] = Cs[(q * 16 + s * 8 + k) * CST + c];
            *(bf16x8*)(vtp + s * 8) = o;
        }
    }
}

// ---------------------------------------------------------------------------
// Kernel 2: per-chunk sums via MFMA: S[e][d] = sum_t Vt[e][t]*Kt[d][t]; ksum[d].
// grid 512, block 256
// ---------------------------------------------------------------------------
__global__ __launch_bounds__(256) void chunk_sum_kernel(
    const short* __restrict__ Ktb, const short* __restrict__ Vt,
    float* __restrict__ Schunk, float* __restrict__ kchunk)
{
    __shared__ short VtL[64 * LDST];
    __shared__ short KtL[64 * LDST];
    __shared__ float ksp[4][64];
    const int bh = blockIdx.x >> 5, c = blockIdx.x & 31;
    const int tid = threadIdx.x;
    const int lane = tid & 63, w = tid >> 6;
    const int fr = lane & 15, fg = lane >> 4;
    #pragma unroll
    for (int it = 0; it < 2; it++) {
        const int qi = it * 256 + tid;           // 0..511
        const int r = qi >> 3, c8 = (qi & 7) * 8;
        *(bf16x8*)&VtL[r * LDST + c8] =
            *(const bf16x8*)(Vt + ((size_t)(bh * HD) + r) * T_SEQ + c * CHUNK + c8);
        *(bf16x8*)&KtL[r * LDST + c8] =
            *(const bf16x8*)(Ktb + ((size_t)(bh * HD) + r) * T_SEQ + c * CHUNK + c8);
    }
    __syncthreads();
    f32x4 acc[4] = {};
    #pragma unroll
    for (int ks = 0; ks < 2; ks++) {
        const bf16x8 av = *(const bf16x8*)&VtL[(w * 16 + fr) * LDST + ks * 32 + fg * 8];
        #pragma unroll
        for (int j = 0; j < 4; j++) {
            const bf16x8 bk = *(const bf16x8*)&KtL[(j * 16 + fr) * LDST + ks * 32 + fg * 8];
            acc[j] = __builtin_amdgcn_mfma_f32_16x16x32_bf16(av, bk, acc[j], 0, 0, 0);
        }
    }
    float* Sout = Schunk + ((size_t)bh * NCHUNK + c) * 4096;   // [e][d]
    #pragma unroll
    for (int j = 0; j < 4; j++)
        #pragma unroll
        for (int reg = 0; reg < 4; reg++)
            Sout[(w * 16 + fg * 4 + reg) * 64 + j * 16 + fr] = acc[j][reg];
    float ps = 0.f;
    #pragma unroll
    for (int t = 0; t < 16; t++) ps += bf2f(KtL[lane * LDST + w * 16 + t]);
    ksp[w][lane] = ps;
    __syncthreads();
    if (tid < 64)
        kchunk[((size_t)bh * NCHUNK + c) * 64 + tid] =
            ksp[0][tid] + ksp[1][tid] + ksp[2][tid] + ksp[3][tid];
}

// ---------------------------------------------------------------------------
// Kernel 3: exclusive prefix over 32 chunks; one scan per thread. grid 260
// ---------------------------------------------------------------------------
__global__ __launch_bounds__(256) void scan_kernel(float* __restrict__ Schunk,
                                                   float* __restrict__ kchunk)
{
    const int gid = blockIdx.x * 256 + threadIdx.x;
    if (blockIdx.x < 256) {
        const int bh = gid >> 12, i = gid & 4095;
        float run = 0.f;
        float* p = Schunk + (size_t)bh * NCHUNK * 4096 + i;
        for (int c = 0; c < NCHUNK; c++) { const float tv = p[c * 4096]; p[c * 4096] = run; run += tv; }
    } else {
        const int idx = gid - 65536;
        const int bh = idx >> 6, d = idx & 63;
        float run = 0.f;
        float* p = kchunk + (size_t)bh * NCHUNK * 64 + d;
        for (int c = 0; c < NCHUNK; c++) { const float tv = p[c * 64]; p[c * 64] = run; run += tv; }
    }
}

// ---------------------------------------------------------------------------
// Kernel 4: intra-chunk via MFMA.
// qn = Qs/(Ksum+eps); A = tril(qn.K^T); attn = qn.Sp^T + A.V^T  (bf16 out)
// grid 512, block 256
// ---------------------------------------------------------------------------
__global__ __launch_bounds__(256) void intra_kernel(
    const short* __restrict__ Qs, const short* __restrict__ Kbf,
    const short* __restrict__ Vt, const float* __restrict__ Schunk,
    const float* __restrict__ kchunk, short* __restrict__ attnb)
{
    __shared__ short B1[64 * LDST];   // Qs, then A
    __shared__ short B2[64 * LDST];   // Sp [e][d]
    __shared__ short KL[64 * LDST];   // K  [s][d]
    __shared__ short VtL[64 * LDST];  // Vt [e][s]
    __shared__ short QnL[64 * LDST];  // qn [t][d]
    __shared__ float gsum[4][64];
    __shared__ float kpre[64];
    const int bh = blockIdx.x >> 5, c = blockIdx.x & 31;
    const int tid = threadIdx.x;
    const int lane = tid & 63, w = tid >> 6;
    const int fr = lane & 15, fg = lane >> 4;
    const size_t tdbase = ((size_t)bh * T_SEQ + c * CHUNK) * HD;
    #pragma unroll
    for (int it = 0; it < 2; it++) {
        const int qi = it * 256 + tid;
        const int r = qi >> 3, c8 = (qi & 7) * 8;
        *(bf16x8*)&B1[r * LDST + c8]  = *(const bf16x8*)(Qs + tdbase + r * HD + c8);
        *(bf16x8*)&KL[r * LDST + c8]  = *(const bf16x8*)(Kbf + tdbase + r * HD + c8);
        *(bf16x8*)&VtL[r * LDST + c8] =
            *(const bf16x8*)(Vt + ((size_t)(bh * HD) + r) * T_SEQ + c * CHUNK + c8);
    }
    {
        const float* Sp = Schunk + ((size_t)bh * NCHUNK + c) * 4096;
        #pragma unroll
        for (int it = 0; it < 4; it++) {
            const int qi = it * 256 + tid;        // 0..1023
            const int r = qi >> 4, c4 = (qi & 15) * 4;
            const float4 v = *(const float4*)(Sp + r * 64 + c4);
            *(s16x4*)&B2[r * LDST + c4] = (s16x4){f2bf(v.x), f2bf(v.y), f2bf(v.z), f2bf(v.w)};
        }
    }
    if (tid < 64) kpre[tid] = kchunk[((size_t)bh * NCHUNK + c) * 64 + tid];
    __syncthreads();
    // group sums of k over t (4 groups of 16)
    {
        float s = 0.f;
        #pragma unroll
        for (int t = 0; t < 16; t++) s += bf2f(KL[(w * 16 + t) * LDST + lane]);
        gsum[w][lane] = s;
    }
    __syncthreads();
    // qn[t][d] = Qs[t][d] / (kpre[d] + cumsum_k + eps)
    {
        float run = kpre[lane];
        for (int gg = 0; gg < w; gg++) run += gsum[gg][lane];
        #pragma unroll
        for (int t0 = 0; t0 < 16; t0++) {
            const int t = w * 16 + t0;
            run += bf2f(KL[t * LDST + lane]);
            const float qv = bf2f(B1[t * LDST + lane]);
            QnL[t * LDST + lane] = f2bf(qv / (run + EPSV));
        }
    }
    __syncthreads();
    // phase 1: A = tril(qn . K^T) -> B1 (bf16)
    {
        f32x4 a1[4] = {};
        #pragma unroll
        for (int ks = 0; ks < 2; ks++) {
            const bf16x8 aq = *(const bf16x8*)&QnL[(w * 16 + fr) * LDST + ks * 32 + fg * 8];
            #pragma unroll
            for (int j = 0; j < 4; j++) {
                const bf16x8 bk = *(const bf16x8*)&KL[(j * 16 + fr) * LDST + ks * 32 + fg * 8];
                a1[j] = __builtin_amdgcn_mfma_f32_16x16x32_bf16(aq, bk, a1[j], 0, 0, 0);
            }
        }
        const int trow = w * 16 + fg * 4;
        #pragma unroll
        for (int j = 0; j < 4; j++)
            #pragma unroll
            for (int reg = 0; reg < 4; reg++) {
                const int t = trow + reg, s = j * 16 + fr;
                B1[t * LDST + s] = (s <= t) ? f2bf(a1[j][reg]) : (short)0;
            }
    }
    __syncthreads();
    // phase 2: attn = qn.Sp^T + A.V^T
    {
        f32x4 a2[4] = {};
        #pragma unroll
        for (int ks = 0; ks < 2; ks++) {
            const bf16x8 aq = *(const bf16x8*)&QnL[(w * 16 + fr) * LDST + ks * 32 + fg * 8];
            const bf16x8 aa = *(const bf16x8*)&B1[(w * 16 + fr) * LDST + ks * 32 + fg * 8];
            #pragma unroll
            for (int j = 0; j < 4; j++) {
                const bf16x8 bs = *(const bf16x8*)&B2[(j * 16 + fr) * LDST + ks * 32 + fg * 8];
                const bf16x8 bv = *(const bf16x8*)&VtL[(j * 16 + fr) * LDST + ks * 32 + fg * 8];
                a2[j] = __builtin_amdgcn_mfma_f32_16x16x32_bf16(aq, bs, a2[j], 0, 0, 0);
                a2[j] = __builtin_amdgcn_mfma_f32_16x16x32_bf16(aa, bv, a2[j], 0, 0, 0);
            }
        }
        short* ap = attnb + tdbase;
        const int trow = w * 16 + fg * 4;
        #pragma unroll
        for (int j = 0; j < 4; j++)
            #pragma unroll
            for (int reg = 0; reg < 4; reg++)
                ap[(trow + reg) * HD + j * 16 + fr] = f2bf(a2[j][reg]);
    }
}

// ---------------------------------------------------------------------------
// Kernel 5: out = attn(permuted) @ Wo^T + bo, 64x64 tile. grid (64,8), 256
// ---------------------------------------------------------------------------
__global__ __launch_bounds__(256) void outproj_mfma_kernel(
    const short* __restrict__ attnb, const short* __restrict__ Wob,
    const float* __restrict__ bo, float* __restrict__ out)
{
    __shared__ short As[64 * 64];
    __shared__ short Bs[64 * 64];
    const int m0 = blockIdx.x * 64;
    const int n0 = blockIdx.y * 64;
    const int tid = threadIdx.x;
    const int lane = tid & 63, w = tid >> 6;
    const int fr = lane & 15, fg = lane >> 4;
    const int lr = lane >> 3, lc = (lane & 7) * 8;
    const int b = m0 >> 11, tbase = m0 & (T_SEQ - 1);
    f32x4 acc[4] = {};
    for (int k0 = 0; k0 < DIMM; k0 += 64) {
        const int h = k0 >> 6;
        #pragma unroll
        for (int it = 0; it < 2; it++) {
            const int r0 = w * 16 + it * 8;
            gload_lds16(attnb + (((size_t)(b * NH + h)) * T_SEQ + tbase + r0 + lr) * HD + lc,
                        &As[r0 * 64]);
            gload_lds16(Wob + (size_t)(n0 + r0 + lr) * DIMM + k0 + lc, &Bs[r0 * 64]);
        }
        __syncthreads();
        #pragma unroll
        for (int ks = 0; ks < 2; ks++) {
            const bf16x8 af = *(const bf16x8*)&As[(w * 16 + fr) * 64 + ks * 32 + fg * 8];
            #pragma unroll
            for (int j = 0; j < 4; j++) {
                const bf16x8 bfr = *(const bf16x8*)&Bs[(j * 16 + fr) * 64 + ks * 32 + fg * 8];
                acc[j] = __builtin_amdgcn_mfma_f32_16x16x32_bf16(af, bfr, acc[j], 0, 0, 0);
            }
        }
        __syncthreads();
    }
    #pragma unroll
    for (int j = 0; j < 4; j++)
        #pragma unroll
        for (int reg = 0; reg < 4; reg++) {
            const int m = m0 + w * 16 + fg * 4 + reg;
            const int n = n0 + j * 16 + fr;
            out[(size_t)m * DIMM + n] = acc[j][reg] + bo[n];
        }
}

// ---------------------------------------------------------------------------
extern "C" void kernel_launch(void* const* d_in, const int* in_sizes, int n_in,
                              void* d_out, int out_size, void* d_ws, size_t ws_size,
                              hipStream_t stream)
{
    const float* x  = (const float*)d_in[0];
    const float* Wq = (const float*)d_in[1];
    const float* Wk = (const float*)d_in[2];
    const float* Wv = (const float*)d_in[3];
    const float* Wo = (const float*)d_in[4];
    const float* bo = (const float*)d_in[5];
    float* out = (float*)d_out;

    const size_t NELEM = (size_t)BB * T_SEQ * DIMM;   // 2,097,152
    short* xb    = (short*)d_ws;                      // [4096][512]
    short* Wcat  = xb + NELEM;                        // [1536][512]
    short* Wob   = Wcat + 786432;                     // [512][512]
    short* Qs    = Wob + 262144;
    short* Kbf   = Qs + NELEM;
    short* Ktb   = Kbf + NELEM;
    short* Vt    = Ktb + NELEM;
    short* attnb = Vt + NELEM;
    float* Schunk = (float*)(attnb + NELEM);                    // [bh][c][e][d]
    float* kchunk = Schunk + (size_t)BB * NH * NCHUNK * 4096;   // [bh][c][d]

    convert_kernel<<<dim3(1536), 256, 0, stream>>>(x, Wq, Wk, Wv, Wo, xb, Wcat, Wob);
    proj_mfma_kernel<<<dim3(24, 64), 256, 0, stream>>>(xb, Wcat, Qs, Kbf, Ktb, Vt);
    chunk_sum_kernel<<<dim3(BB * NH * NCHUNK), 256, 0, stream>>>(Ktb, Vt, Schunk, kchunk);
    scan_kernel<<<dim3(260), 256, 0, stream>>>(Schunk, kchunk);
    intra_kernel<<<dim3(BB * NH * NCHUNK), 256, 0, stream>>>(Qs, Kbf, Vt, Schunk, kchunk, attnb);
    outproj_mfma_kernel<<<dim3(64, 8), 256, 0, stream>>>(attnb, Wob, bo, out);
}

// Round 10
// 56.223 us; speedup vs baseline: 1.1387x; 1.1387x over previous
//
#include <hip/hip_runtime.h>

#define T_SEQ 2048
#define DIMM 512
#define NH 8
#define HD 64
#define BB 2
#define CHUNK 64
#define NCHUNK 32
#define EPSV 1e-6f
#define LDST 72    // bf16 LDS row stride (shorts) for the small kernels
#define CST2 198   // fused epilogue bounce-tile row stride (shorts), 192+6

typedef __attribute__((ext_vector_type(8))) short bf16x8;
typedef __attribute__((ext_vector_type(4))) short s16x4;
typedef __attribute__((ext_vector_type(4))) float f32x4;

static __device__ inline short f2bf(float f) {
    union { float f; unsigned u; } v; v.f = f;
    unsigned r = v.u + 0x7FFFu + ((v.u >> 16) & 1u);
    return (short)(r >> 16);
}
static __device__ inline float bf2f(short s) {
    union { unsigned u; float f; } v; v.u = ((unsigned)(unsigned short)s) << 16;
    return v.f;
}
static __device__ __forceinline__ void gload_lds16(const void* g, void* l) {
    __builtin_amdgcn_global_load_lds(
        (__attribute__((address_space(1))) void*)g,
        (__attribute__((address_space(3))) void*)l, 16, 0, 0);
}

// ---------------------------------------------------------------------------
// Kernel 0: fp32 -> bf16. x -> xb; {Wq,Wk,Wv} -> Wcat[1536][512]; Wo -> Wob.
// grid 1536, block 256
// ---------------------------------------------------------------------------
__global__ __launch_bounds__(256) void convert_kernel(
    const float* __restrict__ x, const float* __restrict__ Wq,
    const float* __restrict__ Wk, const float* __restrict__ Wv,
    const float* __restrict__ Wo,
    short* __restrict__ xb, short* __restrict__ Wcat, short* __restrict__ Wob)
{
    const int u = blockIdx.x * 256 + threadIdx.x;   // 8-float unit id
    const float* src; short* dst;
    if (u < 262144) {
        src = x + (size_t)u * 8; dst = xb + (size_t)u * 8;
    } else {
        const int v = u - 262144;
        const int o = (v & 32767) * 8;
        if (v < 32768)       { src = Wq + o; dst = Wcat + o; }
        else if (v < 65536)  { src = Wk + o; dst = Wcat + 262144 + o; }
        else if (v < 98304)  { src = Wv + o; dst = Wcat + 524288 + o; }
        else                 { src = Wo + o; dst = Wob + o; }
    }
    const float4 a = *(const float4*)src;
    const float4 b = *(const float4*)(src + 4);
    *(bf16x8*)dst = (bf16x8){f2bf(a.x), f2bf(a.y), f2bf(a.z), f2bf(a.w),
                             f2bf(b.x), f2bf(b.y), f2bf(b.z), f2bf(b.w)};
}

// ---------------------------------------------------------------------------
// Kernel 1: FUSED per-(head, chunk) QKV projection + chunk-sum.
// Block (h, mt): 64x192 GEMM (A = xb rows m0..m0+64, B = Wq_h|Wk_h|Wv_h rows),
// swizzled LDS staging; epilogue: softmax(Q)->Qs, elu+1(K)->Kbf+Ktb, V->Vt,
// Schunk[e][d] = V^T.K (8 MFMA from bounce tile), kchunk = colsum(K).
// grid (8, 64), block 256; 32 KB LDS
// ---------------------------------------------------------------------------
__global__ __launch_bounds__(256) void fusedproj_kernel(
    const short* __restrict__ xb, const short* __restrict__ Wcat,
    short* __restrict__ Qs, short* __restrict__ Kbf,
    short* __restrict__ Ktb, short* __restrict__ Vt,
    float* __restrict__ Schunk, float* __restrict__ kchunk)
{
    __shared__ short S[16384];   // 32 KB: As[64][64] | Bs[192][64]; Cs aliases
    short* As = S;
    short* Bs = S + 4096;
    short* Cs = S;               // [64][CST2] = 12672 shorts, aliases As+Bs
    const int h = blockIdx.x;
    const int m0 = blockIdx.y * 64;
    const int b = m0 >> 11;
    const int t0 = m0 & (T_SEQ - 1);
    const int c = t0 >> 6;
    const int bh = b * NH + h;
    const int tid = threadIdx.x;
    const int lane = tid & 63, w = tid >> 6;
    const int fr = lane & 15, fg = lane >> 4;
    const int lr = lane >> 3;
    const int sl8 = ((lane & 7) ^ lr) * 8;   // inverse-swizzled source k-chunk
    const int xr = fr & 7;                   // read-side swizzle key
    f32x4 acc[12] = {};

    for (int k0 = 0; k0 < DIMM; k0 += 64) {
        // stage As: wave w rows w*16..+16 (2 groups of 8)
        #pragma unroll
        for (int it = 0; it < 2; it++) {
            const int r0 = w * 16 + it * 8;
            gload_lds16(xb + (size_t)(m0 + r0 + lr) * DIMM + k0 + sl8, &As[r0 * 64]);
        }
        // stage Bs: wave w rows w*48..+48 (6 groups of 8); row rb -> Wcat row
        #pragma unroll
        for (int it = 0; it < 6; it++) {
            const int rb0 = w * 48 + it * 8;
            const int rb = rb0 + lr;
            const int p = rb >> 6;
            const int gr = p * DIMM + h * 64 + (rb & 63);
            gload_lds16(Wcat + (size_t)gr * DIMM + k0 + sl8, &Bs[rb0 * 64]);
        }
        __syncthreads();
        #pragma unroll
        for (int ks = 0; ks < 2; ks++) {
            const int cc = (((ks << 2) + fg) ^ xr) * 8;
            const bf16x8 af = *(const bf16x8*)&As[(w * 16 + fr) * 64 + cc];
            #pragma unroll
            for (int jj = 0; jj < 12; jj++) {
                const bf16x8 bfr = *(const bf16x8*)&Bs[(jj * 16 + fr) * 64 + cc];
                acc[jj] = __builtin_amdgcn_mfma_f32_16x16x32_bf16(af, bfr, acc[jj], 0, 0, 0);
            }
        }
        __syncthreads();
    }

    // bounce acc -> Cs[64][198] (elu+1 fused for K cols 64..127)
    #pragma unroll
    for (int jj = 0; jj < 12; jj++)
        #pragma unroll
        for (int reg = 0; reg < 4; reg++) {
            float val = acc[jj][reg];
            if (jj >= 4 && jj < 8) val = (val > 0.f) ? (val + 1.f) : __expf(val);
            Cs[(w * 16 + fg * 4 + reg) * CST2 + jj * 16 + fr] = f2bf(val);
        }
    __syncthreads();

    // --- Q softmax + store (threads 0..63) / Kbf row copy (64..127) ---
    if (tid < 64) {
        const int r = tid;
        const unsigned* cr = (const unsigned*)&Cs[r * CST2];   // 32 u32 (cols 0..63)
        unsigned u[32];
        #pragma unroll
        for (int s = 0; s < 32; s++) u[s] = cr[s];
        float mx = -1e30f;
        #pragma unroll
        for (int s = 0; s < 32; s++) {
            mx = fmaxf(mx, bf2f((short)(u[s] & 0xffff)));
            mx = fmaxf(mx, bf2f((short)(u[s] >> 16)));
        }
        float sum = 0.f;
        #pragma unroll
        for (int s = 0; s < 32; s++) {
            sum += __expf(bf2f((short)(u[s] & 0xffff)) - mx);
            sum += __expf(bf2f((short)(u[s] >> 16)) - mx);
        }
        const float inv = 1.f / sum;
        short* qp = Qs + ((size_t)bh * T_SEQ + t0 + r) * HD;
        #pragma unroll
        for (int g = 0; g < 8; g++) {
            bf16x8 o;
            #pragma unroll
            for (int k = 0; k < 4; k++) {
                const unsigned uv = u[g * 4 + k];
                o[2 * k]     = f2bf(__expf(bf2f((short)(uv & 0xffff)) - mx) * inv);
                o[2 * k + 1] = f2bf(__expf(bf2f((short)(uv >> 16)) - mx) * inv);
            }
            *(bf16x8*)(qp + g * 8) = o;
        }
    } else if (tid < 128) {
        const int r = tid - 64;
        const unsigned* cr = (const unsigned*)&Cs[r * CST2 + 64];
        short* kp = Kbf + ((size_t)bh * T_SEQ + t0 + r) * HD;
        #pragma unroll
        for (int g = 0; g < 8; g++) {
            bf16x8 o;
            #pragma unroll
            for (int k = 0; k < 4; k++) {
                const unsigned uv = cr[g * 4 + k];
                o[2 * k]     = (short)(uv & 0xffff);
                o[2 * k + 1] = (short)(uv >> 16);
            }
            *(bf16x8*)(kp + g * 8) = o;
        }
    }
    // --- Ktb / Vt transposes (all 256 threads) ---
    {
        const int col = tid & 63, q = tid >> 6;
        short* ktp = Ktb + ((size_t)bh * HD + col) * T_SEQ + t0 + q * 16;
        short* vtp = Vt  + ((size_t)bh * HD + col) * T_SEQ + t0 + q * 16;
        #pragma unroll
        for (int s = 0; s < 2; s++) {
            bf16x8 ok, ov;
            #pragma unroll
            for (int k = 0; k < 8; k++) {
                ok[k] = Cs[(q * 16 + s * 8 + k) * CST2 + 64 + col];
                ov[k] = Cs[(q * 16 + s * 8 + k) * CST2 + 128 + col];
            }
            *(bf16x8*)(ktp + s * 8) = ok;
            *(bf16x8*)(vtp + s * 8) = ov;
        }
    }
    // --- fused chunk-sum: Schunk[e][d] = sum_t V[t][e]*K[t][d] ---
    {
        f32x4 a2[4] = {};
        #pragma unroll
        for (int ks = 0; ks < 2; ks++) {
            bf16x8 av;
            #pragma unroll
            for (int uu = 0; uu < 8; uu++)
                av[uu] = Cs[(ks * 32 + fg * 8 + uu) * CST2 + 128 + w * 16 + fr];
            #pragma unroll
            for (int jj = 0; jj < 4; jj++) {
                bf16x8 bk;
                #pragma unroll
                for (int uu = 0; uu < 8; uu++)
                    bk[uu] = Cs[(ks * 32 + fg * 8 + uu) * CST2 + 64 + jj * 16 + fr];
                a2[jj] = __builtin_amdgcn_mfma_f32_16x16x32_bf16(av, bk, a2[jj], 0, 0, 0);
            }
        }
        float* Sout = Schunk + ((size_t)bh * NCHUNK + c) * 4096;   // [e][d]
        #pragma unroll
        for (int jj = 0; jj < 4; jj++)
            #pragma unroll
            for (int reg = 0; reg < 4; reg++)
                Sout[(w * 16 + fg * 4 + reg) * 64 + jj * 16 + fr] = a2[jj][reg];
    }
    if (tid < 64) {
        float s = 0.f;
        #pragma unroll
        for (int t = 0; t < 64; t++) s += bf2f(Cs[t * CST2 + 64 + tid]);
        kchunk[((size_t)bh * NCHUNK + c) * 64 + tid] = s;
    }
}

// ---------------------------------------------------------------------------
// Kernel 2: exclusive prefix over 32 chunks; one scan per thread. grid 260
// ---------------------------------------------------------------------------
__global__ __launch_bounds__(256) void scan_kernel(float* __restrict__ Schunk,
                                                   float* __restrict__ kchunk)
{
    const int gid = blockIdx.x * 256 + threadIdx.x;
    if (blockIdx.x < 256) {
        const int bh = gid >> 12, i = gid & 4095;
        float run = 0.f;
        float* p = Schunk + (size_t)bh * NCHUNK * 4096 + i;
        for (int c = 0; c < NCHUNK; c++) { const float tv = p[c * 4096]; p[c * 4096] = run; run += tv; }
    } else {
        const int idx = gid - 65536;
        const int bh = idx >> 6, d = idx & 63;
        float run = 0.f;
        float* p = kchunk + (size_t)bh * NCHUNK * 64 + d;
        for (int c = 0; c < NCHUNK; c++) { const float tv = p[c * 64]; p[c * 64] = run; run += tv; }
    }
}

// ---------------------------------------------------------------------------
// Kernel 3: intra-chunk via MFMA.
// qn = Qs/(Ksum+eps); A = tril(qn.K^T); attn = qn.Sp^T + A.V^T  (bf16 out)
// grid 512, block 256
// ---------------------------------------------------------------------------
__global__ __launch_bounds__(256) void intra_kernel(
    const short* __restrict__ Qs, const short* __restrict__ Kbf,
    const short* __restrict__ Vt, const float* __restrict__ Schunk,
    const float* __restrict__ kchunk, short* __restrict__ attnb)
{
    __shared__ short B1[64 * LDST];   // Qs, then A
    __shared__ short B2[64 * LDST];   // Sp [e][d]
    __shared__ short KL[64 * LDST];   // K  [s][d]
    __shared__ short VtL[64 * LDST];  // Vt [e][s]
    __shared__ short QnL[64 * LDST];  // qn [t][d]
    __shared__ float gsum[4][64];
    __shared__ float kpre[64];
    const int bh = blockIdx.x >> 5, c = blockIdx.x & 31;
    const int tid = threadIdx.x;
    const int lane = tid & 63, w = tid >> 6;
    const int fr = lane & 15, fg = lane >> 4;
    const size_t tdbase = ((size_t)bh * T_SEQ + c * CHUNK) * HD;
    #pragma unroll
    for (int it = 0; it < 2; it++) {
        const int qi = it * 256 + tid;
        const int r = qi >> 3, c8 = (qi & 7) * 8;
        *(bf16x8*)&B1[r * LDST + c8]  = *(const bf16x8*)(Qs + tdbase + r * HD + c8);
        *(bf16x8*)&KL[r * LDST + c8]  = *(const bf16x8*)(Kbf + tdbase + r * HD + c8);
        *(bf16x8*)&VtL[r * LDST + c8] =
            *(const bf16x8*)(Vt + ((size_t)(bh * HD) + r) * T_SEQ + c * CHUNK + c8);
    }
    {
        const float* Sp = Schunk + ((size_t)bh * NCHUNK + c) * 4096;
        #pragma unroll
        for (int it = 0; it < 4; it++) {
            const int qi = it * 256 + tid;        // 0..1023
            const int r = qi >> 4, c4 = (qi & 15) * 4;
            const float4 v = *(const float4*)(Sp + r * 64 + c4);
            *(s16x4*)&B2[r * LDST + c4] = (s16x4){f2bf(v.x), f2bf(v.y), f2bf(v.z), f2bf(v.w)};
        }
    }
    if (tid < 64) kpre[tid] = kchunk[((size_t)bh * NCHUNK + c) * 64 + tid];
    __syncthreads();
    // group sums of k over t (4 groups of 16)
    {
        float s = 0.f;
        #pragma unroll
        for (int t = 0; t < 16; t++) s += bf2f(KL[(w * 16 + t) * LDST + lane]);
        gsum[w][lane] = s;
    }
    __syncthreads();
    // qn[t][d] = Qs[t][d] / (kpre[d] + cumsum_k + eps)
    {
        float run = kpre[lane];
        for (int gg = 0; gg < w; gg++) run += gsum[gg][lane];
        #pragma unroll
        for (int t0 = 0; t0 < 16; t0++) {
            const int t = w * 16 + t0;
            run += bf2f(KL[t * LDST + lane]);
            const float qv = bf2f(B1[t * LDST + lane]);
            QnL[t * LDST + lane] = f2bf(qv / (run + EPSV));
        }
    }
    __syncthreads();
    // phase 1: A = tril(qn . K^T) -> B1 (bf16)
    {
        f32x4 a1[4] = {};
        #pragma unroll
        for (int ks = 0; ks < 2; ks++) {
            const bf16x8 aq = *(const bf16x8*)&QnL[(w * 16 + fr) * LDST + ks * 32 + fg * 8];
            #pragma unroll
            for (int j = 0; j < 4; j++) {
                const bf16x8 bk = *(const bf16x8*)&KL[(j * 16 + fr) * LDST + ks * 32 + fg * 8];
                a1[j] = __builtin_amdgcn_mfma_f32_16x16x32_bf16(aq, bk, a1[j], 0, 0, 0);
            }
        }
        const int trow = w * 16 + fg * 4;
        #pragma unroll
        for (int j = 0; j < 4; j++)
            #pragma unroll
            for (int reg = 0; reg < 4; reg++) {
                const int t = trow + reg, s = j * 16 + fr;
                B1[t * LDST + s] = (s <= t) ? f2bf(a1[j][reg]) : (short)0;
            }
    }
    __syncthreads();
    // phase 2: attn = qn.Sp^T + A.V^T
    {
        f32x4 a2[4] = {};
        #pragma unroll
        for (int ks = 0; ks < 2; ks++) {
            const bf16x8 aq = *(const bf16x8*)&QnL[(w * 16 + fr) * LDST + ks * 32 + fg * 8];
            const bf16x8 aa = *(const bf16x8*)&B1[(w * 16 + fr) * LDST + ks * 32 + fg * 8];
            #pragma unroll
            for (int j = 0; j < 4; j++) {
                const bf16x8 bs = *(const bf16x8*)&B2[(j * 16 + fr) * LDST + ks * 32 + fg * 8];
                const bf16x8 bv = *(const bf16x8*)&VtL[(j * 16 + fr) * LDST + ks * 32 + fg * 8];
                a2[j] = __builtin_amdgcn_mfma_f32_16x16x32_bf16(aq, bs, a2[j], 0, 0, 0);
                a2[j] = __builtin_amdgcn_mfma_f32_16x16x32_bf16(aa, bv, a2[j], 0, 0, 0);
            }
        }
        short* ap = attnb + tdbase;
        const int trow = w * 16 + fg * 4;
        #pragma unroll
        for (int j = 0; j < 4; j++)
            #pragma unroll
            for (int reg = 0; reg < 4; reg++)
                ap[(trow + reg) * HD + j * 16 + fr] = f2bf(a2[j][reg]);
    }
}

// ---------------------------------------------------------------------------
// Kernel 4: out = attn(permuted) @ Wo^T + bo, 64x64 tile. grid (64,8), 256
// ---------------------------------------------------------------------------
__global__ __launch_bounds__(256) void outproj_mfma_kernel(
    const short* __restrict__ attnb, const short* __restrict__ Wob,
    const float* __restrict__ bo, float* __restrict__ out)
{
    __shared__ short As[64 * 64];
    __shared__ short Bs[64 * 64];
    const int m0 = blockIdx.x * 64;
    const int n0 = blockIdx.y * 64;
    const int tid = threadIdx.x;
    const int lane = tid & 63, w = tid >> 6;
    const int fr = lane & 15, fg = lane >> 4;
    const int lr = lane >> 3, lc = (lane & 7) * 8;
    const int b = m0 >> 11, tbase = m0 & (T_SEQ - 1);
    f32x4 acc[4] = {};
    for (int k0 = 0; k0 < DIMM; k0 += 64) {
        const int h = k0 >> 6;
        #pragma unroll
        for (int it = 0; it < 2; it++) {
            const int r0 = w * 16 + it * 8;
            gload_lds16(attnb + (((size_t)(b * NH + h)) * T_SEQ + tbase + r0 + lr) * HD + lc,
                        &As[r0 * 64]);
            gload_lds16(Wob + (size_t)(n0 + r0 + lr) * DIMM + k0 + lc, &Bs[r0 * 64]);
        }
        __syncthreads();
        #pragma unroll
        for (int ks = 0; ks < 2; ks++) {
            const bf16x8 af = *(const bf16x8*)&As[(w * 16 + fr) * 64 + ks * 32 + fg * 8];
            #pragma unroll
            for (int j = 0; j < 4; j++) {
                const bf16x8 bfr = *(const bf16x8*)&Bs[(j * 16 + fr) * 64 + ks * 32 + fg * 8];
                acc[j] = __builtin_amdgcn_mfma_f32_16x16x32_bf16(af, bfr, acc[j], 0, 0, 0);
            }
        }
        __syncthreads();
    }
    #pragma unroll
    for (int j = 0; j < 4; j++)
        #pragma unroll
        for (int reg = 0; reg < 4; reg++) {
            const int m = m0 + w * 16 + fg * 4 + reg;
            const int n = n0 + j * 16 + fr;
            out[(size_t)m * DIMM + n] = acc[j][reg] + bo[n];
        }
}

// ---------------------------------------------------------------------------
extern "C" void kernel_launch(void* const* d_in, const int* in_sizes, int n_in,
                              void* d_out, int out_size, void* d_ws, size_t ws_size,
                              hipStream_t stream)
{
    const float* x  = (const float*)d_in[0];
    const float* Wq = (const float*)d_in[1];
    const float* Wk = (const float*)d_in[2];
    const float* Wv = (const float*)d_in[3];
    const float* Wo = (const float*)d_in[4];
    const float* bo = (const float*)d_in[5];
    float* out = (float*)d_out;

    const size_t NELEM = (size_t)BB * T_SEQ * DIMM;   // 2,097,152
    short* xb    = (short*)d_ws;                      // [4096][512]
    short* Wcat  = xb + NELEM;                        // [1536][512]
    short* Wob   = Wcat + 786432;                     // [512][512]
    short* Qs    = Wob + 262144;
    short* Kbf   = Qs + NELEM;
    short* Ktb   = Kbf + NELEM;
    short* Vt    = Ktb + NELEM;
    short* attnb = Vt + NELEM;
    float* Schunk = (float*)(attnb + NELEM);                    // [bh][c][e][d]
    float* kchunk = Schunk + (size_t)BB * NH * NCHUNK * 4096;   // [bh][c][d]

    convert_kernel<<<dim3(1536), 256, 0, stream>>>(x, Wq, Wk, Wv, Wo, xb, Wcat, Wob);
    fusedproj_kernel<<<dim3(8, 64), 256, 0, stream>>>(xb, Wcat, Qs, Kbf, Ktb, Vt,
                                                      Schunk, kchunk);
    scan_kernel<<<dim3(260), 256, 0, stream>>>(Schunk, kchunk);
    intra_kernel<<<dim3(BB * NH * NCHUNK), 256, 0, stream>>>(Qs, Kbf, Vt, Schunk, kchunk, attnb);
    outproj_mfma_kernel<<<dim3(64, 8), 256, 0, stream>>>(attnb, Wob, bo, out);
}